// Round 6
// baseline (170.580 us; speedup 1.0000x reference)
//
#include <hip/hip_runtime.h>
#include <hip/hip_bf16.h>

typedef __bf16 bf16x8 __attribute__((ext_vector_type(8)));
typedef __bf16 bf16x4 __attribute__((ext_vector_type(4)));
typedef float f32x4 __attribute__((ext_vector_type(4)));
typedef float f32x16 __attribute__((ext_vector_type(16)));

#define NTOK 16384
#define DIN  256
#define DHID 512
#define DOUT 256
#define NEXP 8

#define MFMA32(a, b, c) __builtin_amdgcn_mfma_f32_32x32x16_bf16(a, b, c, 0, 0, 0)
// async global->LDS, 16B/lane; LDS dest = wave-uniform base + lane*16 (HW rule)
#define GLD16(gp, lp)                                                       \
  __builtin_amdgcn_global_load_lds(                                         \
      (__attribute__((address_space(1))) void*)(gp),                        \
      (__attribute__((address_space(3))) void*)(lp), 16, 0, 0)

// ---------------------------------------------------------------------------
// Merged weight prep. blockIdx.x<64: W1 [E][256k][512h] -> w1bf [E][512h][256k]
// (transpose, bf16). Else: W2 [E][512k][256o] -> w2p [E][32ks][2hi][256o][8k]
// packed so phase-B B-frags are single coalesced 1KiB loads.
__global__ __launch_bounds__(256) void wcvt_kernel(const float* __restrict__ w1,
                                                   const float* __restrict__ w2,
                                                   __bf16* __restrict__ w1bf,
                                                   __bf16* __restrict__ w2p) {
  int e = blockIdx.y;
  if (blockIdx.x < 64) {
    int flat = blockIdx.x * 256 + threadIdx.x;  // [0, 16384)
    int kg = flat >> 9;                         // k-group of 8
    int n = flat & 511;                         // hid
    const float* s = w1 + ((size_t)e * 256 + (size_t)kg * 8) * 512 + n;
    bf16x8 t;
#pragma unroll
    for (int j = 0; j < 8; ++j) t[j] = (__bf16)s[(size_t)j * 512];
    *(bf16x8*)(w1bf + (size_t)(e * 512 + n) * 256 + kg * 8) = t;
  } else {
    int flat = (blockIdx.x - 64) * 256 + threadIdx.x;  // [0, 16384)
    int out = flat & 255;
    int khigh = flat >> 8;                      // ks*2+hi in [0,64), k0=khigh*8
    const float* s = w2 + ((size_t)e * 512 + (size_t)khigh * 8) * 256 + out;
    bf16x8 t;
#pragma unroll
    for (int j = 0; j < 8; ++j) t[j] = (__bf16)s[(size_t)j * 256];
    *(bf16x8*)(w2p + (size_t)e * 131072 + (size_t)flat * 8) = t;
  }
}

// ---------------------------------------------------------------------------
// Gating (8 lanes/token, 32 tokens/block) + fused x->bf16 conversion.
// Bucket entry packs the pick slot (0 = top1, 1 = top2) in bit 14.
__global__ __launch_bounds__(256) void gate_kernel(const float* __restrict__ x,
                                                   const float* __restrict__ wg,
                                                   int* __restrict__ cnt,
                                                   int* __restrict__ btok,
                                                   float* __restrict__ bw,
                                                   __bf16* __restrict__ xbf) {
  __shared__ int lcnt[NEXP];
  __shared__ int lbase[NEXP];
  const int tid = threadIdx.x;
  if (tid < NEXP) lcnt[tid] = 0;

  const int sub = tid & 7;        // 32-dim slice
  const int tslot = tid >> 3;     // 0..31
  const int token = blockIdx.x * 32 + tslot;
  const f32x4* xr = (const f32x4*)(x + (size_t)token * DIN + sub * 32);
  const float* wr0 = wg + (size_t)sub * 32 * NEXP;

  bf16x8 xb[4];
  f32x4 p0 = {0.f, 0.f, 0.f, 0.f}, p1 = {0.f, 0.f, 0.f, 0.f};
#pragma unroll
  for (int j4 = 0; j4 < 8; ++j4) {
    f32x4 xv = xr[j4];
    const float* wr = wr0 + j4 * 32;
#pragma unroll
    for (int d = 0; d < 4; ++d) {
      float xs_ = xv[d];
      p0 += xs_ * *(const f32x4*)(wr + 8 * d);
      p1 += xs_ * *(const f32x4*)(wr + 8 * d + 4);
      xb[j4 >> 1][(j4 & 1) * 4 + d] = (__bf16)xs_;
    }
  }
  {
    bf16x8* xdst = (bf16x8*)(xbf + (size_t)token * DIN + sub * 32);
#pragma unroll
    for (int i = 0; i < 4; ++i) xdst[i] = xb[i];
  }

  double acc[NEXP];
#pragma unroll
  for (int d = 0; d < 4; ++d) {
    acc[d] = (double)p0[d];
    acc[4 + d] = (double)p1[d];
  }
#pragma unroll
  for (int off = 1; off < 8; off <<= 1)
#pragma unroll
    for (int e = 0; e < NEXP; ++e) acc[e] += __shfl_xor(acc[e], off, 64);

  __syncthreads();  // lcnt zeroing visible

  int i1 = 0, i2 = 0, o1 = 0, o2 = 0;
  float w1 = 0.f, w2 = 0.f;
  if (sub == 0) {
    double bv1 = acc[0];
#pragma unroll
    for (int e = 1; e < NEXP; ++e)
      if (acc[e] > bv1) { bv1 = acc[e]; i1 = e; }
    double bv2 = -1e300;
#pragma unroll
    for (int e = 0; e < NEXP; ++e)
      if (e != i1 && acc[e] > bv2) { bv2 = acc[e]; i2 = e; }
    float dd = expf((float)(bv2 - bv1));
    w1 = 1.0f / (1.0f + dd);
    w2 = dd * w1;
    o1 = atomicAdd(&lcnt[i1], 1);
    o2 = atomicAdd(&lcnt[i2], 1);
  }
  __syncthreads();
  if (tid < NEXP) lbase[tid] = atomicAdd(&cnt[tid], lcnt[tid]);
  __syncthreads();
  if (sub == 0) {
    int s1 = lbase[i1] + o1, s2 = lbase[i2] + o2;
    btok[i1 * NTOK + s1] = token;           // slot 0
    bw[i1 * NTOK + s1] = w1;
    btok[i2 * NTOK + s2] = token | 16384;   // slot 1 (bit 14)
    bw[i2 * NTOK + s2] = w2;
  }
}

// ---------------------------------------------------------------------------
// Expert FFN, round 6. Key changes vs R5:
//  * W1 staged via LANE-LINEAR global_load_lds (no global-side swizzle ->
//    4-line coalescing per inst instead of up to 64 fragments). Bank safety
//    from a padded 528B row stride (one row per 32-lane-masked GLD16).
//  * W2 never touches LDS: phase-B B-frags are single coalesced 1KiB global
//    loads from the packed w2p layout (register-resident, no barrier).
//  * W1(next chunk) staged right AFTER the hs-barrier so phase B covers the
//    vmcnt drain at the top-of-loop barrier. 2 barriers/chunk.
//  * hs padded to 144B stride; phase B: A=h (tok rows), B=W2 (out cols).
__global__ __launch_bounds__(256, 2) void ffn_kernel(
    const __bf16* __restrict__ xbf, const __bf16* __restrict__ w1bf,
    const __bf16* __restrict__ w2p, const float* __restrict__ b1g,
    const float* __restrict__ b2g, const int* __restrict__ cnt,
    const int* __restrict__ btok, const float* __restrict__ bw,
    __bf16* __restrict__ pout) {
  __shared__ __align__(16) __bf16 wb1[64 * 264];  // [hid64][k256], 528B rows
  __shared__ __align__(16) __bf16 hs[64 * 72];    // [tok64][hid64], 144B rows
  __shared__ int tok[64];
  __shared__ int srow[64];
  __shared__ float wgt[64];
  __shared__ float b2s[DOUT];

  // locate (expert, tile) via prefix over cnt
  int b = blockIdx.x;
  int e = -1, start = 0;
  {
    int a0 = 0;
#pragma unroll
    for (int q = 0; q < NEXP; ++q) {
      int t = (cnt[q] + 63) >> 6;
      if (e < 0 && b < a0 + t) { e = q; start = (b - a0) * 64; }
      a0 += t;
    }
  }
  if (e < 0) return;
  const int ce = cnt[e];

  const int tid = threadIdx.x;
  if (tid < 64) {
    int idx = start + tid;
    bool v = idx < ce;
    int entry = v ? btok[e * NTOK + idx] : 0;
    int t = entry & 16383;
    tok[tid] = t;
    srow[tid] = (entry >> 14) * NTOK + t;
    wgt[tid] = v ? bw[e * NTOK + idx] : 0.0f;
  }
  b2s[tid] = b2g[e * DOUT + tid];
  __syncthreads();

  const int lane = tid & 63;
  const int wid = tid >> 6;      // 0..3
  const int l31 = lane & 31;
  const int hi = lane >> 5;      // k-half selector
  const int wh = wid >> 1;       // phase A: hid half
  const int wt = wid & 1;        // phase A: tok half

  // x as phase-A B-operand in registers: B[k][tok-col], col = wt*32+l31.
  bf16x8 xB[16];
  {
    const __bf16* xr = xbf + (size_t)tok[wt * 32 + l31] * DIN + hi * 8;
#pragma unroll
    for (int kw = 0; kw < 16; ++kw) xB[kw] = *(const bf16x8*)(xr + kw * 16);
  }

  const __bf16* w1e = w1bf + (size_t)e * DHID * DIN;
  const __bf16* w2e = w2p + (size_t)e * 131072;

  // lane-linear W1 chunk staging: one 512B row per 32-lane GLD16.
  auto stage = [&](int hc) {
    if (lane < 32) {
#pragma unroll
      for (int j = 0; j < 16; ++j) {
        int row = wid * 16 + j;
        GLD16(w1e + (size_t)(hc * 64 + row) * DIN + l31 * 8,
              (char*)wb1 + row * 528);
      }
    }
  };
  stage(0);

  f32x16 acc[2][2];  // [out-tile][tok-tile]
#pragma unroll
  for (int at = 0; at < 2; ++at)
#pragma unroll
    for (int bt = 0; bt < 2; ++bt)
#pragma unroll
      for (int r = 0; r < 16; ++r) acc[at][bt][r] = 0.f;

  for (int hc = 0; hc < 8; ++hc) {
    __syncthreads();  // staging visible (drain covered by prev phase B)

    // ---- phase A: S[hid32 x tok32] = W1c-half x x-half, K=256
    f32x16 S;
#pragma unroll
    for (int r = 0; r < 16; ++r) S[r] = 0.f;
#pragma unroll
    for (int kw = 0; kw < 16; ++kw) {
      int row = wh * 32 + l31;
      bf16x8 a = *(const bf16x8*)((const char*)wb1 + row * 528 + kw * 32 + hi * 16);
      S = MFMA32(a, xB[kw], S);
    }
    // bias + relu -> hs: lane owns tok col m, 4-consecutive-hid row groups
#pragma unroll
    for (int q = 0; q < 4; ++q) {
      int hl = wh * 32 + q * 8 + hi * 4;   // local hid, 4-aligned
      f32x4 bv = *(const f32x4*)(b1g + e * DHID + hc * 64 + hl);
      bf16x4 pk;
#pragma unroll
      for (int r = 0; r < 4; ++r)
        pk[r] = (__bf16)fmaxf(S[4 * q + r] + bv[r], 0.f);
      int m = wt * 32 + l31;
      *(bf16x4*)((char*)hs + m * 144 + hl * 2) = pk;
    }
    __syncthreads();  // hs visible; wb1 reads done -> safe to restage

    if (hc < 7) stage(hc + 1);  // drain covered by phase B below

    // ---- phase B: acc[tok64 x out64-per-wave] += h x W2c (B from global)
#pragma unroll
    for (int kw = 0; kw < 4; ++kw) {
      bf16x8 hf[2], wf[2];
#pragma unroll
      for (int bt = 0; bt < 2; ++bt)
        hf[bt] = *(const bf16x8*)((const char*)hs + (bt * 32 + l31) * 144 +
                                  kw * 32 + hi * 16);
#pragma unroll
      for (int at = 0; at < 2; ++at)
        wf[at] = *(const bf16x8*)(w2e + (size_t)(hc * 4 + kw) * 4096 +
                                  hi * 2048 + (wid * 64 + at * 32 + l31) * 8);
      acc[0][0] = MFMA32(hf[0], wf[0], acc[0][0]);
      acc[0][1] = MFMA32(hf[1], wf[0], acc[0][1]);
      acc[1][0] = MFMA32(hf[0], wf[1], acc[1][0]);
      acc[1][1] = MFMA32(hf[1], wf[1], acc[1][1]);
    }
  }

  // ---- epilogue: pout[srow[t]][o] = bf16(w * (acc + b2))
  // D[tok][out]: col=out=l31(+base), row tok = (r&3)+8*(r>>2)+4*hi (+bt*32)
#pragma unroll
  for (int at = 0; at < 2; ++at) {
    int outc = wid * 64 + at * 32 + l31;
    float b2v = b2s[outc];
#pragma unroll
    for (int bt = 0; bt < 2; ++bt) {
#pragma unroll
      for (int q = 0; q < 4; ++q) {
#pragma unroll
        for (int r = 0; r < 4; ++r) {
          int tokr = bt * 32 + q * 8 + hi * 4 + r;
          if (start + tokr < ce) {
            float v = wgt[tokr] * (acc[at][bt][4 * q + r] + b2v);
            pout[(size_t)srow[tokr] * DOUT + outc] = (__bf16)v;
          }
        }
      }
    }
  }
}

// ---------------------------------------------------------------------------
// out[t][c] = pout[0][t][c] + pout[1][t][c]   (streaming, 8 elems/thread)
__global__ __launch_bounds__(256) void combine_kernel(const __bf16* __restrict__ pout,
                                                      float* __restrict__ out) {
  int f = blockIdx.x * 256 + threadIdx.x;  // [0, NTOK*DOUT/8)
  bf16x8 a = *(const bf16x8*)(pout + (size_t)f * 8);
  bf16x8 b = *(const bf16x8*)(pout + (size_t)NTOK * DOUT + (size_t)f * 8);
  float4 o0, o1;
  o0.x = (float)a[0] + (float)b[0];
  o0.y = (float)a[1] + (float)b[1];
  o0.z = (float)a[2] + (float)b[2];
  o0.w = (float)a[3] + (float)b[3];
  o1.x = (float)a[4] + (float)b[4];
  o1.y = (float)a[5] + (float)b[5];
  o1.z = (float)a[6] + (float)b[6];
  o1.w = (float)a[7] + (float)b[7];
  float4* dst = (float4*)(out + (size_t)f * 8);
  dst[0] = o0;
  dst[1] = o1;
}

// ---------------------------------------------------------------------------
extern "C" void kernel_launch(void* const* d_in, const int* in_sizes, int n_in,
                              void* d_out, int out_size, void* d_ws, size_t ws_size,
                              hipStream_t stream) {
  const float* x = (const float*)d_in[0];
  const float* Wg = (const float*)d_in[1];
  const float* W1 = (const float*)d_in[2];
  const float* b1 = (const float*)d_in[3];
  const float* W2 = (const float*)d_in[4];
  const float* b2 = (const float*)d_in[5];
  float* out = (float*)d_out;

  char* ws = (char*)d_ws;
  int* cnt = (int*)(ws + 0);                    //      32 B
  int* btok = (int*)(ws + 256);                 //  512 KiB
  float* bw = (float*)(ws + 524544);            //  512 KiB
  __bf16* xbf = (__bf16*)(ws + 1048832);        //    8 MiB
  __bf16* w1bf = (__bf16*)(ws + 9437440);       //    2 MiB
  __bf16* w2p = (__bf16*)(ws + 11534592);       //    2 MiB
  __bf16* pout = (__bf16*)(ws + 13631744);      //   16 MiB (end ~29 MiB)

  hipMemsetAsync(cnt, 0, NEXP * sizeof(int), stream);

  wcvt_kernel<<<dim3(128, NEXP), dim3(256), 0, stream>>>(W1, W2, w1bf, w2p);
  gate_kernel<<<dim3(NTOK / 32), dim3(256), 0, stream>>>(x, Wg, cnt, btok, bw, xbf);
  ffn_kernel<<<dim3(520), dim3(256), 0, stream>>>(xbf, w1bf, w2p, b1, b2,
                                                  cnt, btok, bw, pout);
  combine_kernel<<<dim3(NTOK * DOUT / 8 / 256), dim3(256), 0, stream>>>(pout, out);
}

// Round 7
// 166.387 us; speedup vs baseline: 1.0252x; 1.0252x over previous
//
#include <hip/hip_runtime.h>
#include <hip/hip_bf16.h>

typedef __bf16 bf16x8 __attribute__((ext_vector_type(8)));
typedef __bf16 bf16x4 __attribute__((ext_vector_type(4)));
typedef float f32x4 __attribute__((ext_vector_type(4)));
typedef float f32x16 __attribute__((ext_vector_type(16)));

#define NTOK 16384
#define DIN  256
#define DHID 512
#define DOUT 256
#define NEXP 8

#define MFMA32(a, b, c) __builtin_amdgcn_mfma_f32_32x32x16_bf16(a, b, c, 0, 0, 0)
// async global->LDS, 16B/lane; LDS dest = wave-uniform base + lane*16 (HW rule)
#define GLD16(gp, lp)                                                       \
  __builtin_amdgcn_global_load_lds(                                         \
      (__attribute__((address_space(1))) void*)(gp),                        \
      (__attribute__((address_space(3))) void*)(lp), 16, 0, 0)

// ---------------------------------------------------------------------------
// Fused prep: b<512 -> gate (+x->bf16); b<1024 -> W1 transpose+cvt;
// else -> W2 transpose+cvt. One dispatch, parts run concurrently.
__global__ __launch_bounds__(256) void prep_kernel(
    const float* __restrict__ x, const float* __restrict__ wg,
    const float* __restrict__ w1, const float* __restrict__ w2,
    int* __restrict__ cnt, int* __restrict__ btok, float* __restrict__ bw,
    __bf16* __restrict__ xbf, __bf16* __restrict__ w1bf,
    __bf16* __restrict__ w2bf) {
  __shared__ int lcnt[NEXP];
  __shared__ int lbase[NEXP];
  const int b = blockIdx.x;
  const int tid = threadIdx.x;

  if (b >= 512) {
    if (b < 1024) {  // W1 [E][256k][512h] -> w1bf [E][512h][256k]
      int e = (b - 512) >> 6;
      int flat = ((b - 512) & 63) * 256 + tid;  // [0, 16384)
      int kg = flat >> 9;
      int n = flat & 511;
      const float* s = w1 + ((size_t)e * 256 + (size_t)kg * 8) * 512 + n;
      bf16x8 t;
#pragma unroll
      for (int j = 0; j < 8; ++j) t[j] = (__bf16)s[(size_t)j * 512];
      *(bf16x8*)(w1bf + (size_t)(e * 512 + n) * 256 + kg * 8) = t;
    } else {         // W2 [E][512k][256o] -> w2bf [E][256o][512k]
      int e = (b - 1024) >> 6;
      int flat = ((b - 1024) & 63) * 256 + tid;  // [0, 16384)
      int kg = flat >> 8;
      int n = flat & 255;
      const float* s = w2 + ((size_t)e * 512 + (size_t)kg * 8) * 256 + n;
      bf16x8 t;
#pragma unroll
      for (int j = 0; j < 8; ++j) t[j] = (__bf16)s[(size_t)j * 256];
      *(bf16x8*)(w2bf + (size_t)(e * 256 + n) * 512 + kg * 8) = t;
    }
    return;
  }

  // ---- gate part: 8 lanes/token, 32 tokens/block ----
  if (tid < NEXP) lcnt[tid] = 0;

  const int sub = tid & 7;
  const int tslot = tid >> 3;
  const int token = b * 32 + tslot;
  const f32x4* xr = (const f32x4*)(x + (size_t)token * DIN + sub * 32);
  const float* wr0 = wg + (size_t)sub * 32 * NEXP;

  bf16x8 xb[4];
  f32x4 p0 = {0.f, 0.f, 0.f, 0.f}, p1 = {0.f, 0.f, 0.f, 0.f};
#pragma unroll
  for (int j4 = 0; j4 < 8; ++j4) {
    f32x4 xv = xr[j4];
    const float* wr = wr0 + j4 * 32;
#pragma unroll
    for (int d = 0; d < 4; ++d) {
      float xs_ = xv[d];
      p0 += xs_ * *(const f32x4*)(wr + 8 * d);
      p1 += xs_ * *(const f32x4*)(wr + 8 * d + 4);
      xb[j4 >> 1][(j4 & 1) * 4 + d] = (__bf16)xs_;
    }
  }
  {
    bf16x8* xdst = (bf16x8*)(xbf + (size_t)token * DIN + sub * 32);
#pragma unroll
    for (int i = 0; i < 4; ++i) xdst[i] = xb[i];
  }

  double acc[NEXP];
#pragma unroll
  for (int d = 0; d < 4; ++d) {
    acc[d] = (double)p0[d];
    acc[4 + d] = (double)p1[d];
  }
#pragma unroll
  for (int off = 1; off < 8; off <<= 1)
#pragma unroll
    for (int e = 0; e < NEXP; ++e) acc[e] += __shfl_xor(acc[e], off, 64);

  __syncthreads();  // lcnt zeroing visible

  int i1 = 0, i2 = 0, o1 = 0, o2 = 0;
  float w1s = 0.f, w2s = 0.f;
  if (sub == 0) {
    double bv1 = acc[0];
#pragma unroll
    for (int e = 1; e < NEXP; ++e)
      if (acc[e] > bv1) { bv1 = acc[e]; i1 = e; }
    double bv2 = -1e300;
#pragma unroll
    for (int e = 0; e < NEXP; ++e)
      if (e != i1 && acc[e] > bv2) { bv2 = acc[e]; i2 = e; }
    float dd = expf((float)(bv2 - bv1));
    w1s = 1.0f / (1.0f + dd);
    w2s = dd * w1s;
    o1 = atomicAdd(&lcnt[i1], 1);
    o2 = atomicAdd(&lcnt[i2], 1);
  }
  __syncthreads();
  if (tid < NEXP) lbase[tid] = atomicAdd(&cnt[tid], lcnt[tid]);
  __syncthreads();
  if (sub == 0) {
    int s1 = lbase[i1] + o1, s2 = lbase[i2] + o2;
    btok[i1 * NTOK + s1] = token;           // slot 0
    bw[i1 * NTOK + s1] = w1s;
    btok[i2 * NTOK + s2] = token | 16384;   // slot 1 (bit 14)
    bw[i2 * NTOK + s2] = w2s;
  }
}

// ---------------------------------------------------------------------------
// Expert FFN, round 7: R5's inner structure (best measured) + XCD-affinity
// expert mapping. Grid = exactly 512 blocks (2/CU, no tail generation);
// expert = blockIdx & 7 so (with the %8 round-robin block->XCD heuristic)
// each expert's 64 blocks share one XCD and its 0.5 MB of bf16 weights stays
// L2-resident instead of thrashing (R6 showed 6x HBM re-fetch of weights).
// slot = blockIdx >> 3 strides over the expert's 64-token tiles.
__global__ __launch_bounds__(256, 2) void ffn_kernel(
    const __bf16* __restrict__ xbf, const __bf16* __restrict__ w1bf,
    const __bf16* __restrict__ w2bf, const float* __restrict__ b1g,
    const float* __restrict__ b2g, const int* __restrict__ cnt,
    const int* __restrict__ btok, const float* __restrict__ bw,
    __bf16* __restrict__ pout) {
  __shared__ __align__(16) __bf16 wb1[64 * 256];   // [hid64][k256], slot^(n&31)
  __shared__ __align__(16) __bf16 wb2[256 * 64];   // [out256][k64], slot^(n&7)
  __shared__ __align__(16) __bf16 hs[64 * 64];     // [tok64][hid64], slot^(m&7)
  __shared__ int tok[64];
  __shared__ int srow[64];
  __shared__ float wgt[64];
  __shared__ float b2s[DOUT];

  const int e = blockIdx.x & 7;      // expert -> XCD affinity
  const int slot = blockIdx.x >> 3;  // 0..63
  const int ce = cnt[e];
  const int nt = (ce + 63) >> 6;

  const int tid = threadIdx.x;
  b2s[tid] = b2g[e * DOUT + tid];

  const int lane = tid & 63;
  const int wid = tid >> 6;      // 0..3
  const int hi = lane >> 5;      // k-half selector
  const int l31 = lane & 31;
  const int wh = wid >> 1;       // phase A: hid half
  const int wt = wid & 1;        // phase A: tok half
  const int wo = wid;            // phase B: out quarter

  const __bf16* w1e = w1bf + (size_t)e * DHID * DIN;
  const __bf16* w2e = w2bf + (size_t)e * DOUT * DHID;

  for (int t = slot; t < nt; t += 64) {
    const int start = t * 64;
    __syncthreads();  // prev tile's epilogue LDS reads done

    if (tid < 64) {
      int idx = start + tid;
      bool v = idx < ce;
      int entry = v ? btok[e * NTOK + idx] : 0;
      int tk = entry & 16383;
      tok[tid] = tk;
      srow[tid] = (entry >> 14) * NTOK + tk;
      wgt[tid] = v ? bw[e * NTOK + idx] : 0.0f;
    }
    __syncthreads();

    // x as phase-A B-operand in registers: B[k][tok-col], col = wt*32+l31.
    bf16x8 xB[16];
    {
      const __bf16* xr = xbf + (size_t)tok[wt * 32 + l31] * DIN + hi * 8;
#pragma unroll
      for (int kw = 0; kw < 16; ++kw) xB[kw] = *(const bf16x8*)(xr + kw * 16);
    }

    f32x16 acc[2][2];
#pragma unroll
    for (int ai = 0; ai < 2; ++ai)
#pragma unroll
      for (int bi = 0; bi < 2; ++bi)
#pragma unroll
        for (int r = 0; r < 16; ++r) acc[ai][bi][r] = 0.f;

    for (int hc = 0; hc < 8; ++hc) {
      __syncthreads();  // prev chunk's readers done with wb1/wb2/hs

      // stage W1c (32 KiB) + W2c (32 KiB); swizzle via global-address permute
#pragma unroll
      for (int j = 0; j < 8; ++j) {
        int W = wid * 8 + j;               // 1 KiB window
        int n1 = 2 * W + hi;               // wb1 row
        int s1 = l31 ^ (n1 & 31);
        GLD16(w1e + (size_t)(hc * 64 + n1) * DIN + s1 * 8, wb1 + W * 512);
        int n2 = 8 * W + (lane >> 3);      // wb2 row
        int s2 = (lane & 7) ^ (n2 & 7);
        GLD16(w2e + (size_t)n2 * DHID + hc * 64 + s2 * 8, wb2 + W * 512);
      }
      __syncthreads();  // staging visible

      // ---- phase A: S[hid32 x tok32] = W1c-half x x-half, K=256
      f32x16 S;
#pragma unroll
      for (int r = 0; r < 16; ++r) S[r] = 0.f;
#pragma unroll
      for (int kw = 0; kw < 16; ++kw) {
        int row = wh * 32 + l31;
        int s = (kw * 2 + hi) ^ (row & 31);
        bf16x8 a = *(const bf16x8*)((const char*)wb1 + row * 512 + s * 16);
        S = MFMA32(a, xB[kw], S);
      }
      // bias + relu -> hs (8B swizzled writes)
#pragma unroll
      for (int g = 0; g < 4; ++g) {
        int hl = wh * 32 + 8 * g + 4 * hi;   // local hid, 4-aligned
        f32x4 bv = *(const f32x4*)(b1g + e * DHID + hc * 64 + hl);
        bf16x4 pk;
#pragma unroll
        for (int r = 0; r < 4; ++r)
          pk[r] = (__bf16)fmaxf(S[4 * g + r] + bv[r], 0.f);
        int m = wt * 32 + l31;               // token row
        int slt = (hl >> 3) ^ (m & 7);
        *(bf16x4*)((char*)hs + m * 128 + slt * 16 + (hl & 7) * 2) = pk;
      }
      __syncthreads();  // hs visible

      // ---- phase B: acc[out64 x tok64] += W2c x h, K=64
#pragma unroll
      for (int kw = 0; kw < 4; ++kw) {
        bf16x8 wf[2], hf[2];
#pragma unroll
        for (int ai = 0; ai < 2; ++ai) {
          int row = wo * 64 + ai * 32 + l31;
          int s = (kw * 2 + hi) ^ (row & 7);
          wf[ai] = *(const bf16x8*)((const char*)wb2 + row * 128 + s * 16);
        }
#pragma unroll
        for (int bi = 0; bi < 2; ++bi) {
          int m = bi * 32 + l31;
          int s = (kw * 2 + hi) ^ (m & 7);
          hf[bi] = *(const bf16x8*)((const char*)hs + m * 128 + s * 16);
        }
        acc[0][0] = MFMA32(wf[0], hf[0], acc[0][0]);
        acc[0][1] = MFMA32(wf[0], hf[1], acc[0][1]);
        acc[1][0] = MFMA32(wf[1], hf[0], acc[1][0]);
        acc[1][1] = MFMA32(wf[1], hf[1], acc[1][1]);
      }
    }

    // ---- epilogue: pout[srow[t]][o] = bf16(w * (acc + b2))
#pragma unroll
    for (int bi = 0; bi < 2; ++bi) {
      int tm = bi * 32 + l31;
      if (start + tm < ce) {
        float wv = wgt[tm];
        __bf16* prow = pout + (size_t)srow[tm] * DOUT;
#pragma unroll
        for (int ai = 0; ai < 2; ++ai) {
#pragma unroll
          for (int g = 0; g < 4; ++g) {
            int o0 = wo * 64 + ai * 32 + 8 * g + 4 * hi;
            f32x4 bv = *(const f32x4*)(&b2s[o0]);
            bf16x4 pk;
#pragma unroll
            for (int r = 0; r < 4; ++r)
              pk[r] = (__bf16)(wv * (acc[ai][bi][4 * g + r] + bv[r]));
            *(bf16x4*)(prow + o0) = pk;
          }
        }
      }
    }
  }
}

// ---------------------------------------------------------------------------
// out[t][c] = pout[0][t][c] + pout[1][t][c]   (streaming, 8 elems/thread)
__global__ __launch_bounds__(256) void combine_kernel(const __bf16* __restrict__ pout,
                                                      float* __restrict__ out) {
  int f = blockIdx.x * 256 + threadIdx.x;  // [0, NTOK*DOUT/8)
  bf16x8 a = *(const bf16x8*)(pout + (size_t)f * 8);
  bf16x8 b = *(const bf16x8*)(pout + (size_t)NTOK * DOUT + (size_t)f * 8);
  float4 o0, o1;
  o0.x = (float)a[0] + (float)b[0];
  o0.y = (float)a[1] + (float)b[1];
  o0.z = (float)a[2] + (float)b[2];
  o0.w = (float)a[3] + (float)b[3];
  o1.x = (float)a[4] + (float)b[4];
  o1.y = (float)a[5] + (float)b[5];
  o1.z = (float)a[6] + (float)b[6];
  o1.w = (float)a[7] + (float)b[7];
  float4* dst = (float4*)(out + (size_t)f * 8);
  dst[0] = o0;
  dst[1] = o1;
}

// ---------------------------------------------------------------------------
extern "C" void kernel_launch(void* const* d_in, const int* in_sizes, int n_in,
                              void* d_out, int out_size, void* d_ws, size_t ws_size,
                              hipStream_t stream) {
  const float* x = (const float*)d_in[0];
  const float* Wg = (const float*)d_in[1];
  const float* W1 = (const float*)d_in[2];
  const float* b1 = (const float*)d_in[3];
  const float* W2 = (const float*)d_in[4];
  const float* b2 = (const float*)d_in[5];
  float* out = (float*)d_out;

  char* ws = (char*)d_ws;
  int* cnt = (int*)(ws + 0);                    //      32 B
  int* btok = (int*)(ws + 256);                 //  512 KiB
  float* bw = (float*)(ws + 524544);            //  512 KiB
  __bf16* xbf = (__bf16*)(ws + 1048832);        //    8 MiB
  __bf16* w1bf = (__bf16*)(ws + 9437440);       //    2 MiB
  __bf16* w2bf = (__bf16*)(ws + 11534592);      //    2 MiB
  __bf16* pout = (__bf16*)(ws + 13631744);      //   16 MiB (end ~29 MiB)

  hipMemsetAsync(cnt, 0, NEXP * sizeof(int), stream);

  prep_kernel<<<dim3(1536), dim3(256), 0, stream>>>(x, Wg, W1, W2, cnt, btok,
                                                    bw, xbf, w1bf, w2bf);
  ffn_kernel<<<dim3(512), dim3(256), 0, stream>>>(xbf, w1bf, w2bf, b1, b2,
                                                  cnt, btok, bw, pout);
  combine_kernel<<<dim3(NTOK * DOUT / 8 / 256), dim3(256), 0, stream>>>(pout, out);
}

// Round 8
// 157.615 us; speedup vs baseline: 1.0823x; 1.0557x over previous
//
#include <hip/hip_runtime.h>
#include <hip/hip_bf16.h>

typedef __bf16 bf16x8 __attribute__((ext_vector_type(8)));
typedef __bf16 bf16x4 __attribute__((ext_vector_type(4)));
typedef float f32x4 __attribute__((ext_vector_type(4)));
typedef float f32x16 __attribute__((ext_vector_type(16)));

#define NTOK 16384
#define DIN  256
#define DHID 512
#define DOUT 256
#define NEXP 8

#define MFMA32(a, b, c) __builtin_amdgcn_mfma_f32_32x32x16_bf16(a, b, c, 0, 0, 0)
// async global->LDS, 16B/lane; LDS dest = wave-uniform base + lane*16 (HW rule)
#define GLD16(gp, lp)                                                       \
  __builtin_amdgcn_global_load_lds(                                         \
      (__attribute__((address_space(1))) void*)(gp),                        \
      (__attribute__((address_space(3))) void*)(lp), 16, 0, 0)

// ---------------------------------------------------------------------------
// Fused prep: b<512 -> gate (+x->bf16); b<1024 -> W1 transpose+cvt;
// else -> W2 transpose+cvt.
__global__ __launch_bounds__(256) void prep_kernel(
    const float* __restrict__ x, const float* __restrict__ wg,
    const float* __restrict__ w1, const float* __restrict__ w2,
    int* __restrict__ cnt, int* __restrict__ btok, float* __restrict__ bw,
    __bf16* __restrict__ xbf, __bf16* __restrict__ w1bf,
    __bf16* __restrict__ w2bf) {
  __shared__ int lcnt[NEXP];
  __shared__ int lbase[NEXP];
  const int b = blockIdx.x;
  const int tid = threadIdx.x;

  if (b >= 512) {
    if (b < 1024) {  // W1 [E][256k][512h] -> w1bf [E][512h][256k]
      int e = (b - 512) >> 6;
      int flat = ((b - 512) & 63) * 256 + tid;  // [0, 16384)
      int kg = flat >> 9;
      int n = flat & 511;
      const float* s = w1 + ((size_t)e * 256 + (size_t)kg * 8) * 512 + n;
      bf16x8 t;
#pragma unroll
      for (int j = 0; j < 8; ++j) t[j] = (__bf16)s[(size_t)j * 512];
      *(bf16x8*)(w1bf + (size_t)(e * 512 + n) * 256 + kg * 8) = t;
    } else {         // W2 [E][512k][256o] -> w2bf [E][256o][512k]
      int e = (b - 1024) >> 6;
      int flat = ((b - 1024) & 63) * 256 + tid;  // [0, 16384)
      int kg = flat >> 8;
      int n = flat & 255;
      const float* s = w2 + ((size_t)e * 512 + (size_t)kg * 8) * 256 + n;
      bf16x8 t;
#pragma unroll
      for (int j = 0; j < 8; ++j) t[j] = (__bf16)s[(size_t)j * 256];
      *(bf16x8*)(w2bf + (size_t)(e * 256 + n) * 512 + kg * 8) = t;
    }
    return;
  }

  // ---- gate part: 8 lanes/token, 32 tokens/block ----
  if (tid < NEXP) lcnt[tid] = 0;

  const int sub = tid & 7;
  const int tslot = tid >> 3;
  const int token = b * 32 + tslot;
  const f32x4* xr = (const f32x4*)(x + (size_t)token * DIN + sub * 32);
  const float* wr0 = wg + (size_t)sub * 32 * NEXP;

  bf16x8 xb[4];
  f32x4 p0 = {0.f, 0.f, 0.f, 0.f}, p1 = {0.f, 0.f, 0.f, 0.f};
#pragma unroll
  for (int j4 = 0; j4 < 8; ++j4) {
    f32x4 xv = xr[j4];
    const float* wr = wr0 + j4 * 32;
#pragma unroll
    for (int d = 0; d < 4; ++d) {
      float xs_ = xv[d];
      p0 += xs_ * *(const f32x4*)(wr + 8 * d);
      p1 += xs_ * *(const f32x4*)(wr + 8 * d + 4);
      xb[j4 >> 1][(j4 & 1) * 4 + d] = (__bf16)xs_;
    }
  }
  {
    bf16x8* xdst = (bf16x8*)(xbf + (size_t)token * DIN + sub * 32);
#pragma unroll
    for (int i = 0; i < 4; ++i) xdst[i] = xb[i];
  }

  double acc[NEXP];
#pragma unroll
  for (int d = 0; d < 4; ++d) {
    acc[d] = (double)p0[d];
    acc[4 + d] = (double)p1[d];
  }
#pragma unroll
  for (int off = 1; off < 8; off <<= 1)
#pragma unroll
    for (int e = 0; e < NEXP; ++e) acc[e] += __shfl_xor(acc[e], off, 64);

  __syncthreads();  // lcnt zeroing visible

  int i1 = 0, i2 = 0, o1 = 0, o2 = 0;
  float w1s = 0.f, w2s = 0.f;
  if (sub == 0) {
    double bv1 = acc[0];
#pragma unroll
    for (int e = 1; e < NEXP; ++e)
      if (acc[e] > bv1) { bv1 = acc[e]; i1 = e; }
    double bv2 = -1e300;
#pragma unroll
    for (int e = 0; e < NEXP; ++e)
      if (e != i1 && acc[e] > bv2) { bv2 = acc[e]; i2 = e; }
    float dd = expf((float)(bv2 - bv1));
    w1s = 1.0f / (1.0f + dd);
    w2s = dd * w1s;
    o1 = atomicAdd(&lcnt[i1], 1);
    o2 = atomicAdd(&lcnt[i2], 1);
  }
  __syncthreads();
  if (tid < NEXP) lbase[tid] = atomicAdd(&cnt[tid], lcnt[tid]);
  __syncthreads();
  if (sub == 0) {
    int s1 = lbase[i1] + o1, s2 = lbase[i2] + o2;
    btok[i1 * NTOK + s1] = token;           // slot 0
    bw[i1 * NTOK + s1] = w1s;
    btok[i2 * NTOK + s2] = token | 16384;   // slot 1 (bit 14)
    bw[i2 * NTOK + s2] = w2s;
  }
}

// ---------------------------------------------------------------------------
// Expert FFN, round 8 = R5 structure (best measured) + per-block CHUNK
// ROTATION. All ~512 co-resident blocks previously staged the IDENTICAL
// 64 KB weight chunk in lockstep -> all L2 requests hammer the same few
// banks/sets (no multicast on CDNA), serializing staging (T2). Rotating the
// chunk order by (blockIdx>>3)&7 spreads concurrent reads over 8 distinct
// chunk regions (x8 XCD copies). fp32 accumulation is order-safe.
// Also: phase-A S split into kw-parity accumulators (breaks 16-deep chain).
__global__ __launch_bounds__(256, 2) void ffn_kernel(
    const __bf16* __restrict__ xbf, const __bf16* __restrict__ w1bf,
    const __bf16* __restrict__ w2bf, const float* __restrict__ b1g,
    const float* __restrict__ b2g, const int* __restrict__ cnt,
    const int* __restrict__ btok, const float* __restrict__ bw,
    __bf16* __restrict__ pout) {
  __shared__ __align__(16) __bf16 wb1[64 * 256];   // [hid64][k256], slot^(n&31)
  __shared__ __align__(16) __bf16 wb2[256 * 64];   // [out256][k64], slot^(n&7)
  __shared__ __align__(16) __bf16 hs[64 * 64];     // [tok64][hid64], slot^(m&7)
  __shared__ int tok[64];
  __shared__ int srow[64];
  __shared__ float wgt[64];
  __shared__ float b2s[DOUT];

  // locate (expert, tile) via prefix over cnt (exact grid, no tails)
  int b = blockIdx.x;
  int e = -1, start = 0;
  {
    int a0 = 0;
#pragma unroll
    for (int q = 0; q < NEXP; ++q) {
      int t = (cnt[q] + 63) >> 6;
      if (e < 0 && b < a0 + t) { e = q; start = (b - a0) * 64; }
      a0 += t;
    }
  }
  if (e < 0) return;
  const int ce = cnt[e];
  const int rot = (blockIdx.x >> 3) & 7;  // chunk-phase decorrelation

  const int tid = threadIdx.x;
  if (tid < 64) {
    int idx = start + tid;
    bool v = idx < ce;
    int entry = v ? btok[e * NTOK + idx] : 0;
    int tk = entry & 16383;
    tok[tid] = tk;
    srow[tid] = (entry >> 14) * NTOK + tk;
    wgt[tid] = v ? bw[e * NTOK + idx] : 0.0f;
  }
  b2s[tid] = b2g[e * DOUT + tid];
  __syncthreads();

  const int lane = tid & 63;
  const int wid = tid >> 6;      // 0..3
  const int hi = lane >> 5;      // k-half selector
  const int l31 = lane & 31;
  const int wh = wid >> 1;       // phase A: hid half
  const int wt = wid & 1;        // phase A: tok half
  const int wo = wid;            // phase B: out quarter

  // x as phase-A B-operand in registers: B[k][tok-col], col = wt*32+l31.
  bf16x8 xB[16];
  {
    const __bf16* xr = xbf + (size_t)tok[wt * 32 + l31] * DIN + hi * 8;
#pragma unroll
    for (int kw = 0; kw < 16; ++kw) xB[kw] = *(const bf16x8*)(xr + kw * 16);
  }

  const __bf16* w1e = w1bf + (size_t)e * DHID * DIN;
  const __bf16* w2e = w2bf + (size_t)e * DOUT * DHID;

  f32x16 acc[2][2];
#pragma unroll
  for (int ai = 0; ai < 2; ++ai)
#pragma unroll
    for (int bi = 0; bi < 2; ++bi)
#pragma unroll
      for (int r = 0; r < 16; ++r) acc[ai][bi][r] = 0.f;

  for (int hc0 = 0; hc0 < 8; ++hc0) {
    const int hc = (hc0 + rot) & 7;  // rotated chunk index
    __syncthreads();  // prev chunk's readers done with wb1/wb2/hs

    // stage W1c (32 KiB) + W2c (32 KiB); swizzle via global-address permute
#pragma unroll
    for (int j = 0; j < 8; ++j) {
      int W = wid * 8 + j;               // 1 KiB window
      int n1 = 2 * W + hi;               // wb1 row
      int s1 = l31 ^ (n1 & 31);
      GLD16(w1e + (size_t)(hc * 64 + n1) * DIN + s1 * 8, wb1 + W * 512);
      int n2 = 8 * W + (lane >> 3);      // wb2 row
      int s2 = (lane & 7) ^ (n2 & 7);
      GLD16(w2e + (size_t)n2 * DHID + hc * 64 + s2 * 8, wb2 + W * 512);
    }
    __syncthreads();  // staging visible

    // ---- phase A: S[hid32 x tok32] = W1c-half x x-half, K=256
    f32x16 Sp[2];
#pragma unroll
    for (int r = 0; r < 16; ++r) { Sp[0][r] = 0.f; Sp[1][r] = 0.f; }
#pragma unroll
    for (int kw = 0; kw < 16; ++kw) {
      int row = wh * 32 + l31;
      int s = (kw * 2 + hi) ^ (row & 31);
      bf16x8 a = *(const bf16x8*)((const char*)wb1 + row * 512 + s * 16);
      Sp[kw & 1] = MFMA32(a, xB[kw], Sp[kw & 1]);
    }
    f32x16 S = Sp[0] + Sp[1];
    // bias + relu -> hs (8B swizzled writes)
#pragma unroll
    for (int g = 0; g < 4; ++g) {
      int hl = wh * 32 + 8 * g + 4 * hi;   // local hid, 4-aligned
      f32x4 bv = *(const f32x4*)(b1g + e * DHID + hc * 64 + hl);
      bf16x4 pk;
#pragma unroll
      for (int r = 0; r < 4; ++r)
        pk[r] = (__bf16)fmaxf(S[4 * g + r] + bv[r], 0.f);
      int m = wt * 32 + l31;               // token row
      int slt = (hl >> 3) ^ (m & 7);
      *(bf16x4*)((char*)hs + m * 128 + slt * 16 + (hl & 7) * 2) = pk;
    }
    __syncthreads();  // hs visible

    // ---- phase B: acc[out64 x tok64] += W2c x h, K=64
#pragma unroll
    for (int kw = 0; kw < 4; ++kw) {
      bf16x8 wf[2], hf[2];
#pragma unroll
      for (int ai = 0; ai < 2; ++ai) {
        int row = wo * 64 + ai * 32 + l31;
        int s = (kw * 2 + hi) ^ (row & 7);
        wf[ai] = *(const bf16x8*)((const char*)wb2 + row * 128 + s * 16);
      }
#pragma unroll
      for (int bi = 0; bi < 2; ++bi) {
        int m = bi * 32 + l31;
        int s = (kw * 2 + hi) ^ (m & 7);
        hf[bi] = *(const bf16x8*)((const char*)hs + m * 128 + s * 16);
      }
      acc[0][0] = MFMA32(wf[0], hf[0], acc[0][0]);
      acc[0][1] = MFMA32(wf[0], hf[1], acc[0][1]);
      acc[1][0] = MFMA32(wf[1], hf[0], acc[1][0]);
      acc[1][1] = MFMA32(wf[1], hf[1], acc[1][1]);
    }
  }

  // ---- epilogue: pout[srow[t]][o] = bf16(w * (acc + b2))
#pragma unroll
  for (int bi = 0; bi < 2; ++bi) {
    int tm = bi * 32 + l31;
    if (start + tm < ce) {
      float wv = wgt[tm];
      __bf16* prow = pout + (size_t)srow[tm] * DOUT;
#pragma unroll
      for (int ai = 0; ai < 2; ++ai) {
#pragma unroll
        for (int g = 0; g < 4; ++g) {
          int o0 = wo * 64 + ai * 32 + 8 * g + 4 * hi;
          f32x4 bv = *(const f32x4*)(&b2s[o0]);
          bf16x4 pk;
#pragma unroll
          for (int r = 0; r < 4; ++r)
            pk[r] = (__bf16)(wv * (acc[ai][bi][4 * g + r] + bv[r]));
          *(bf16x4*)(prow + o0) = pk;
        }
      }
    }
  }
}

// ---------------------------------------------------------------------------
// out[t][c] = pout[0][t][c] + pout[1][t][c]   (streaming, 8 elems/thread)
__global__ __launch_bounds__(256) void combine_kernel(const __bf16* __restrict__ pout,
                                                      float* __restrict__ out) {
  int f = blockIdx.x * 256 + threadIdx.x;  // [0, NTOK*DOUT/8)
  bf16x8 a = *(const bf16x8*)(pout + (size_t)f * 8);
  bf16x8 b = *(const bf16x8*)(pout + (size_t)NTOK * DOUT + (size_t)f * 8);
  float4 o0, o1;
  o0.x = (float)a[0] + (float)b[0];
  o0.y = (float)a[1] + (float)b[1];
  o0.z = (float)a[2] + (float)b[2];
  o0.w = (float)a[3] + (float)b[3];
  o1.x = (float)a[4] + (float)b[4];
  o1.y = (float)a[5] + (float)b[5];
  o1.z = (float)a[6] + (float)b[6];
  o1.w = (float)a[7] + (float)b[7];
  float4* dst = (float4*)(out + (size_t)f * 8);
  dst[0] = o0;
  dst[1] = o1;
}

// ---------------------------------------------------------------------------
extern "C" void kernel_launch(void* const* d_in, const int* in_sizes, int n_in,
                              void* d_out, int out_size, void* d_ws, size_t ws_size,
                              hipStream_t stream) {
  const float* x = (const float*)d_in[0];
  const float* Wg = (const float*)d_in[1];
  const float* W1 = (const float*)d_in[2];
  const float* b1 = (const float*)d_in[3];
  const float* W2 = (const float*)d_in[4];
  const float* b2 = (const float*)d_in[5];
  float* out = (float*)d_out;

  char* ws = (char*)d_ws;
  int* cnt = (int*)(ws + 0);                    //      32 B
  int* btok = (int*)(ws + 256);                 //  512 KiB
  float* bw = (float*)(ws + 524544);            //  512 KiB
  __bf16* xbf = (__bf16*)(ws + 1048832);        //    8 MiB
  __bf16* w1bf = (__bf16*)(ws + 9437440);       //    2 MiB
  __bf16* w2bf = (__bf16*)(ws + 11534592);      //    2 MiB
  __bf16* pout = (__bf16*)(ws + 13631744);      //   16 MiB (end ~29 MiB)

  hipMemsetAsync(cnt, 0, NEXP * sizeof(int), stream);

  prep_kernel<<<dim3(1536), dim3(256), 0, stream>>>(x, Wg, W1, W2, cnt, btok,
                                                    bw, xbf, w1bf, w2bf);
  ffn_kernel<<<dim3(520), dim3(256), 0, stream>>>(xbf, w1bf, w2bf, b1, b2,
                                                  cnt, btok, bw, pout);
  combine_kernel<<<dim3(NTOK * DOUT / 8 / 256), dim3(256), 0, stream>>>(pout, out);
}